// Round 1
// baseline (964.787 us; speedup 1.0000x reference)
//
#include <hip/hip_runtime.h>
#include <hip/hip_bf16.h>

// BasicBlock sparse conv: output-centric gather conv with bf16 MFMA.
//   nbr[o][k] = input row feeding output o at offset k (N_VOX = sentinel -> zero row)
//   conv: h[o][:] = sum_{k=0..26} xb[nbr_or_self][:] @ W[k]   (MFMA 16x16x32 bf16)
//   BN stats via block-partial reduce + atomics; BN+relu fused into elementwise passes.

#define N_VOX 200000
#define P_PAIR 65536
#define EPS_BN 1e-5f

typedef __attribute__((ext_vector_type(8))) short bf16x8;   // 8 bf16 = 4 VGPRs
typedef __attribute__((ext_vector_type(4))) float f32x4;

// ---------------- prep kernels ----------------

__global__ void fill_kernel(int* __restrict__ nbr, float* __restrict__ sums) {
    long idx = (long)blockIdx.x * 256 + threadIdx.x;
    if (idx < (long)N_VOX * 26) nbr[idx] = N_VOX;   // sentinel -> zero row
    if (idx < 256) sums[idx] = 0.0f;                // sum1/sq1/sum2/sq2
}

__global__ void scatter_kernel(const int* __restrict__ out_maps,
                               const int* __restrict__ in_maps,
                               int* __restrict__ nbr) {
    int idx = blockIdx.x * 256 + threadIdx.x;       // < 26*65536
    int o = out_maps[idx];
    if (o < N_VOX) {
        int k = idx >> 16;                          // P_PAIR == 65536
        nbr[(long)o * 26 + k] = in_maps[idx];
    }
}

__global__ void cast_x_kernel(const float* __restrict__ x,
                              __hip_bfloat16* __restrict__ xb) {
    long i = ((long)blockIdx.x * 256 + threadIdx.x) * 4;
    if (i >= (long)(N_VOX + 1) * 64) return;
    __hip_bfloat16 t[4];
    if (i < (long)N_VOX * 64) {
        float4 v = *(const float4*)(x + i);
        t[0] = __float2bfloat16(v.x); t[1] = __float2bfloat16(v.y);
        t[2] = __float2bfloat16(v.z); t[3] = __float2bfloat16(v.w);
    } else {
        t[0] = t[1] = t[2] = t[3] = __float2bfloat16(0.0f);  // zero row N
    }
    *(ushort4*)(xb + i) = *(ushort4*)t;
}

// WT[k][d][c] = W[k][c][d]  (bf16, so B-fragments are contiguous 16B per lane)
__global__ void cast_w_kernel(const float* __restrict__ W1, const float* __restrict__ W2,
                              __hip_bfloat16* __restrict__ W1T, __hip_bfloat16* __restrict__ W2T) {
    int idx = blockIdx.x * 256 + threadIdx.x;
    if (idx >= 27 * 4096) return;
    int k = idx >> 12, rem = idx & 4095;
    int d = rem >> 6, c = rem & 63;
    int src = k * 4096 + c * 64 + d;
    W1T[idx] = __float2bfloat16(W1[src]);
    W2T[idx] = __float2bfloat16(W2[src]);
}

// ---------------- conv kernel ----------------
// block = 4 waves; wave w computes rows [blockIdx*64 + w*16, +16) x all 64 cols.
// A frag (16x32): lane holds row m=lane&15, k = quad*8+j  -> 16B load from xb row
// B frag (32x16): lane holds col d=lane&15, k = quad*8+j  -> 16B load from WT[k][d]
// C/D: col = lane&15, row = quad*4 + reg

__global__ __launch_bounds__(256) void conv_kernel(
    const __hip_bfloat16* __restrict__ xb,   // [(N+1)*64]
    const __hip_bfloat16* __restrict__ WT,   // [27*64*64]
    const int* __restrict__ nbr,             // [N*26]
    float* __restrict__ h)                   // [N*64]
{
    const int tid  = threadIdx.x;
    const int lane = tid & 63;
    const int wave = tid >> 6;
    const int m    = lane & 15;
    const int quad = lane >> 4;
    const int base = blockIdx.x * 64 + wave * 16;   // N_VOX % 64 == 0
    const int o    = base + m;

    // prefetch the 26 neighbor indices for this lane's row
    const int* __restrict__ nrow = nbr + (long)o * 26;
    int nbs[26];
#pragma unroll
    for (int j = 0; j < 26; ++j) nbs[j] = nrow[j];

    f32x4 acc0 = {0.f,0.f,0.f,0.f};
    f32x4 acc1 = {0.f,0.f,0.f,0.f};
    f32x4 acc2 = {0.f,0.f,0.f,0.f};
    f32x4 acc3 = {0.f,0.f,0.f,0.f};

    const __hip_bfloat16* __restrict__ wbase = WT + m * 64 + quad * 8;

#pragma unroll
    for (int k = 0; k < 27; ++k) {
        int nb = (k == 13) ? o : nbs[k - (k > 13 ? 1 : 0)];
        const __hip_bfloat16* ar = xb + (long)nb * 64 + quad * 8;
        bf16x8 a0 = *(const bf16x8*)(ar);         // k 0..31
        bf16x8 a1 = *(const bf16x8*)(ar + 32);    // k 32..63
        const __hip_bfloat16* wk = wbase + k * 4096;
        bf16x8 b00 = *(const bf16x8*)(wk);
        bf16x8 b01 = *(const bf16x8*)(wk + 32);
        bf16x8 b10 = *(const bf16x8*)(wk + 1024);
        bf16x8 b11 = *(const bf16x8*)(wk + 1056);
        bf16x8 b20 = *(const bf16x8*)(wk + 2048);
        bf16x8 b21 = *(const bf16x8*)(wk + 2080);
        bf16x8 b30 = *(const bf16x8*)(wk + 3072);
        bf16x8 b31 = *(const bf16x8*)(wk + 3104);
        acc0 = __builtin_amdgcn_mfma_f32_16x16x32_bf16(a0, b00, acc0, 0, 0, 0);
        acc1 = __builtin_amdgcn_mfma_f32_16x16x32_bf16(a0, b10, acc1, 0, 0, 0);
        acc2 = __builtin_amdgcn_mfma_f32_16x16x32_bf16(a0, b20, acc2, 0, 0, 0);
        acc3 = __builtin_amdgcn_mfma_f32_16x16x32_bf16(a0, b30, acc3, 0, 0, 0);
        acc0 = __builtin_amdgcn_mfma_f32_16x16x32_bf16(a1, b01, acc0, 0, 0, 0);
        acc1 = __builtin_amdgcn_mfma_f32_16x16x32_bf16(a1, b11, acc1, 0, 0, 0);
        acc2 = __builtin_amdgcn_mfma_f32_16x16x32_bf16(a1, b21, acc2, 0, 0, 0);
        acc3 = __builtin_amdgcn_mfma_f32_16x16x32_bf16(a1, b31, acc3, 0, 0, 0);
    }

    float* hp = h + (long)(base + quad * 4) * 64 + m;
#pragma unroll
    for (int r = 0; r < 4; ++r) {
        hp[r * 64 +  0] = acc0[r];
        hp[r * 64 + 16] = acc1[r];
        hp[r * 64 + 32] = acc2[r];
        hp[r * 64 + 48] = acc3[r];
    }
}

// ---------------- BN stats reduce ----------------

__global__ void reduce_kernel(const float* __restrict__ h, float* __restrict__ sums) {
    int c  = threadIdx.x & 63;
    int r0 = threadIdx.x >> 6;   // 0..3
    float s = 0.f, q = 0.f;
    for (long row = blockIdx.x * 4 + r0; row < N_VOX; row += (long)gridDim.x * 4) {
        float v = h[row * 64 + c];
        s += v; q += v * v;
    }
    __shared__ float ls[256], lq[256];
    ls[threadIdx.x] = s; lq[threadIdx.x] = q;
    __syncthreads();
    if (threadIdx.x < 64) {
        s = ls[threadIdx.x] + ls[threadIdx.x + 64] + ls[threadIdx.x + 128] + ls[threadIdx.x + 192];
        q = lq[threadIdx.x] + lq[threadIdx.x + 64] + lq[threadIdx.x + 128] + lq[threadIdx.x + 192];
        atomicAdd(&sums[c], s);
        atomicAdd(&sums[64 + c], q);
    }
}

// ---------------- BN1 + relu + cast to bf16 (conv2 input) ----------------

__global__ void bnrelu_kernel(const float* __restrict__ h, const float* __restrict__ sums,
                              const float* __restrict__ gamma, const float* __restrict__ beta,
                              __hip_bfloat16* __restrict__ hb) {
    long i = ((long)blockIdx.x * 256 + threadIdx.x) * 4;
    if (i >= (long)(N_VOX + 1) * 64) return;
    __hip_bfloat16 t[4];
    if (i < (long)N_VOX * 64) {
        int c0 = (int)(i & 63);
        float4 v = *(const float4*)(h + i);
        float vv[4] = {v.x, v.y, v.z, v.w};
#pragma unroll
        for (int j = 0; j < 4; ++j) {
            int c = c0 + j;
            float mu  = sums[c] * (1.0f / N_VOX);
            float var = sums[64 + c] * (1.0f / N_VOX) - mu * mu;
            float rs  = rsqrtf(var + EPS_BN);
            float val = gamma[c] * (vv[j] - mu) * rs + beta[c];
            t[j] = __float2bfloat16(fmaxf(val, 0.0f));
        }
    } else {
        t[0] = t[1] = t[2] = t[3] = __float2bfloat16(0.0f);   // zero row N
    }
    *(ushort4*)(hb + i) = *(ushort4*)t;
}

// ---------------- BN2 + residual + relu -> d_out ----------------

__global__ void final_kernel(const float* __restrict__ h, const float* __restrict__ x,
                             const float* __restrict__ sums, const float* __restrict__ gamma,
                             const float* __restrict__ beta, float* __restrict__ out) {
    long i = ((long)blockIdx.x * 256 + threadIdx.x) * 4;
    if (i >= (long)N_VOX * 64) return;
    int c0 = (int)(i & 63);
    float4 v  = *(const float4*)(h + i);
    float4 xr = *(const float4*)(x + i);
    float vv[4] = {v.x, v.y, v.z, v.w};
    float xx[4] = {xr.x, xr.y, xr.z, xr.w};
    float oo[4];
#pragma unroll
    for (int j = 0; j < 4; ++j) {
        int c = c0 + j;
        float mu  = sums[c] * (1.0f / N_VOX);
        float var = sums[64 + c] * (1.0f / N_VOX) - mu * mu;
        float rs  = rsqrtf(var + EPS_BN);
        float val = gamma[c] * (vv[j] - mu) * rs + beta[c] + xx[j];
        oo[j] = fmaxf(val, 0.0f);
    }
    float4 ov = {oo[0], oo[1], oo[2], oo[3]};
    *(float4*)(out + i) = ov;
}

// ---------------- launcher ----------------

extern "C" void kernel_launch(void* const* d_in, const int* in_sizes, int n_in,
                              void* d_out, int out_size, void* d_ws, size_t ws_size,
                              hipStream_t stream) {
    const float* x      = (const float*)d_in[0];
    const float* W1     = (const float*)d_in[1];
    const float* gamma1 = (const float*)d_in[2];
    const float* beta1  = (const float*)d_in[3];
    const float* W2     = (const float*)d_in[4];
    const float* gamma2 = (const float*)d_in[5];
    const float* beta2  = (const float*)d_in[6];
    const int* in_maps  = (const int*)d_in[7];
    const int* out_maps = (const int*)d_in[8];
    float* out = (float*)d_out;

    char* ws = (char*)d_ws;
    size_t off = 0;
    auto alloc = [&](size_t bytes) -> void* {
        void* p = ws + off;
        off = (off + bytes + 255) & ~(size_t)255;
        return p;
    };
    int* nbr            = (int*)alloc((size_t)N_VOX * 26 * 4);              // 20.8 MB
    __hip_bfloat16* xb  = (__hip_bfloat16*)alloc((size_t)(N_VOX + 1) * 64 * 2); // 25.6 MB (reused as h1b)
    __hip_bfloat16* W1T = (__hip_bfloat16*)alloc((size_t)27 * 4096 * 2);
    __hip_bfloat16* W2T = (__hip_bfloat16*)alloc((size_t)27 * 4096 * 2);
    float* h            = (float*)alloc((size_t)N_VOX * 64 * 4);            // 51.2 MB
    float* sums         = (float*)alloc(256 * 4);
    __hip_bfloat16* h1b = xb;   // xb dead after conv1; reuse for BN1(relu) output

    const long elem_x = (long)(N_VOX + 1) * 64;

    fill_kernel   <<<(N_VOX * 26 + 255) / 256, 256, 0, stream>>>(nbr, sums);
    scatter_kernel<<<26 * P_PAIR / 256, 256, 0, stream>>>(out_maps, in_maps, nbr);
    cast_x_kernel <<<(int)((elem_x / 4 + 255) / 256), 256, 0, stream>>>(x, xb);
    cast_w_kernel <<<(27 * 4096 + 255) / 256, 256, 0, stream>>>(W1, W2, W1T, W2T);

    conv_kernel   <<<N_VOX / 64, 256, 0, stream>>>(xb, W1T, nbr, h);
    reduce_kernel <<<512, 256, 0, stream>>>(h, sums);
    bnrelu_kernel <<<(int)((elem_x / 4 + 255) / 256), 256, 0, stream>>>(h, sums, gamma1, beta1, h1b);

    conv_kernel   <<<N_VOX / 64, 256, 0, stream>>>(h1b, W2T, nbr, h);
    reduce_kernel <<<512, 256, 0, stream>>>(h, sums + 128);
    final_kernel  <<<(int)(((long)N_VOX * 64 / 4 + 255) / 256), 256, 0, stream>>>(h, x, sums + 128, gamma2, beta2, out);
}

// Round 2
// 643.992 us; speedup vs baseline: 1.4981x; 1.4981x over previous
//
#include <hip/hip_runtime.h>
#include <hip/hip_bf16.h>

// BasicBlock sparse conv v2: output-centric gather conv, bf16 MFMA,
// k-major neighbor planes + software-pipelined gathers + fused BN-stat reduce.
//   nbrT[p][o] = input row feeding output o for weight plane p (p=13 identity).
//   conv: h[o][:] = sum_p xb[nbrT[p][o]][:] @ W[p]
// Wave computes 32 rows x 64 cols; A gathers prefetched 1 k ahead, indices 5 ahead.

#define N_VOX 200000
#define NP 200064            // padded rows: 1563 blocks * 128 rows
#define P_PAIR 65536
#define EPS_BN 1e-5f

typedef __attribute__((ext_vector_type(8))) short bf16x8;   // 8 bf16 = 4 VGPRs
typedef __attribute__((ext_vector_type(4))) float f32x4;

// ---------------- prep kernels ----------------

__global__ void fill_kernel(int* __restrict__ nbrT, float* __restrict__ sums) {
    int p = blockIdx.y;                                   // plane 0..26
    long i = ((long)blockIdx.x * 256 + threadIdx.x) * 4;  // element in plane
    if (i < NP) {
        int4 v;
        if (p == 13) {   // identity plane (center tap); pad rows -> zero row
            v.x = (i + 0 < N_VOX) ? (int)i + 0 : N_VOX;
            v.y = (i + 1 < N_VOX) ? (int)i + 1 : N_VOX;
            v.z = (i + 2 < N_VOX) ? (int)i + 2 : N_VOX;
            v.w = (i + 3 < N_VOX) ? (int)i + 3 : N_VOX;
        } else {
            v.x = v.y = v.z = v.w = N_VOX;                // sentinel -> zero row
        }
        *(int4*)(nbrT + (long)p * NP + i) = v;
    }
    if (p == 0 && blockIdx.x == 0 && threadIdx.x < 64) {  // zero sums[256]
        float4 z = {0.f, 0.f, 0.f, 0.f};
        ((float4*)sums)[threadIdx.x] = z;
    }
}

__global__ void scatter_kernel(const int* __restrict__ out_maps,
                               const int* __restrict__ in_maps,
                               int* __restrict__ nbrT) {
    int idx = blockIdx.x * 256 + threadIdx.x;       // < 26*65536
    int o = out_maps[idx];
    if (o < N_VOX) {
        int k = idx >> 16;                          // offset index 0..25
        int p = k + (k >= 13);                      // weight plane (skip center)
        nbrT[(long)p * NP + o] = in_maps[idx];
    }
}

__global__ void cast_x_kernel(const float* __restrict__ x,
                              __hip_bfloat16* __restrict__ xb) {
    long i = ((long)blockIdx.x * 256 + threadIdx.x) * 4;
    if (i >= (long)(N_VOX + 1) * 64) return;
    __hip_bfloat16 t[4];
    if (i < (long)N_VOX * 64) {
        float4 v = *(const float4*)(x + i);
        t[0] = __float2bfloat16(v.x); t[1] = __float2bfloat16(v.y);
        t[2] = __float2bfloat16(v.z); t[3] = __float2bfloat16(v.w);
    } else {
        t[0] = t[1] = t[2] = t[3] = __float2bfloat16(0.0f);  // zero row N
    }
    *(ushort4*)(xb + i) = *(ushort4*)t;
}

// WT[k][d][c] = W[k][c][d]  (bf16; B-fragments are contiguous 16B per lane)
__global__ void cast_w_kernel(const float* __restrict__ W1, const float* __restrict__ W2,
                              __hip_bfloat16* __restrict__ W1T, __hip_bfloat16* __restrict__ W2T) {
    int idx = blockIdx.x * 256 + threadIdx.x;
    if (idx >= 27 * 4096) return;
    int k = idx >> 12, rem = idx & 4095;
    int d = rem >> 6, c = rem & 63;
    int src = k * 4096 + c * 64 + d;
    W1T[idx] = __float2bfloat16(W1[src]);
    W2T[idx] = __float2bfloat16(W2[src]);
}

// ---------------- conv kernel ----------------
// block = 4 waves; wave computes 32 rows (2 MFMA row-tiles) x 64 cols.
// A frag: lane holds row m=lane&15 of tile, k-seg quad -> 16B load from xb row.
// B frag: lane holds d=ct*16+m, k-seg quad -> 16B load from WT (shared by both tiles).
// C/D: col = lane&15 (+16*ct), row = quad*4 + reg.
// Pipeline: indices prefetched 5 planes ahead; A fragments 1 plane ahead.
// Epilogue: fused per-channel sum/sumsq (BN stats) via LDS + atomics.

__global__ __launch_bounds__(256, 4) void conv_kernel(
    const __hip_bfloat16* __restrict__ xb,   // [(N+1)*64]
    const __hip_bfloat16* __restrict__ WT,   // [27*64*64]
    const int* __restrict__ nbrT,            // [27*NP]
    float* __restrict__ h,                   // [N*64]
    float* __restrict__ sums)                // [128]: sum[64], sumsq[64]
{
    const int tid  = threadIdx.x;
    const int lane = tid & 63;
    const int wave = tid >> 6;
    const int m    = lane & 15;
    const int quad = lane >> 4;
    const int rbase = (blockIdx.x * 4 + wave) * 32;   // 32 rows per wave
    const int o0 = rbase + m;                          // tile0 row for this lane

    const int* __restrict__ ip = nbrT + o0;            // tile1 at +16

    f32x4 acc[8];   // [tile*4 + ctile]
#pragma unroll
    for (int i = 0; i < 8; ++i) acc[i] = (f32x4){0.f, 0.f, 0.f, 0.f};

    const __hip_bfloat16* __restrict__ wfrag = WT + m * 64 + quad * 8;

    // rotating index stages (5 deep) and A-fragment stages (2 deep)
    int id0[5], id1[5];
    bf16x8 A[2][2][2];   // [stage][tile][half]

#pragma unroll
    for (int s = 0; s < 5; ++s) {
        id0[s] = ip[(long)s * NP];
        id1[s] = ip[(long)s * NP + 16];
    }
    {   // A for k=0
        const __hip_bfloat16* r0 = xb + (long)id0[0] * 64 + quad * 8;
        A[0][0][0] = *(const bf16x8*)r0;  A[0][0][1] = *(const bf16x8*)(r0 + 32);
        const __hip_bfloat16* r1 = xb + (long)id1[0] * 64 + quad * 8;
        A[0][1][0] = *(const bf16x8*)r1;  A[0][1][1] = *(const bf16x8*)(r1 + 32);
    }

#pragma unroll
    for (int k = 0; k < 27; ++k) {
        const int cs = k & 1, ns = cs ^ 1;
        // prefetch indices for plane k+5
        if (k + 5 < 27) {
            id0[(k + 5) % 5] = ip[(long)(k + 5) * NP];
            id1[(k + 5) % 5] = ip[(long)(k + 5) * NP + 16];
        }
        // prefetch A fragments for plane k+1
        if (k + 1 < 27) {
            const __hip_bfloat16* r0 = xb + (long)id0[(k + 1) % 5] * 64 + quad * 8;
            A[ns][0][0] = *(const bf16x8*)r0;  A[ns][0][1] = *(const bf16x8*)(r0 + 32);
            const __hip_bfloat16* r1 = xb + (long)id1[(k + 1) % 5] * 64 + quad * 8;
            A[ns][1][0] = *(const bf16x8*)r1;  A[ns][1][1] = *(const bf16x8*)(r1 + 32);
        }
        // B fragments for plane k (shared by both row tiles)
        const __hip_bfloat16* wk = wfrag + k * 4096;
        bf16x8 b0[4], b1[4];
#pragma unroll
        for (int ct = 0; ct < 4; ++ct) {
            b0[ct] = *(const bf16x8*)(wk + ct * 1024);
            b1[ct] = *(const bf16x8*)(wk + ct * 1024 + 32);
        }
#pragma unroll
        for (int ct = 0; ct < 4; ++ct) {
            acc[ct]     = __builtin_amdgcn_mfma_f32_16x16x32_bf16(A[cs][0][0], b0[ct], acc[ct], 0, 0, 0);
            acc[ct]     = __builtin_amdgcn_mfma_f32_16x16x32_bf16(A[cs][0][1], b1[ct], acc[ct], 0, 0, 0);
            acc[4 + ct] = __builtin_amdgcn_mfma_f32_16x16x32_bf16(A[cs][1][0], b0[ct], acc[4 + ct], 0, 0, 0);
            acc[4 + ct] = __builtin_amdgcn_mfma_f32_16x16x32_bf16(A[cs][1][1], b1[ct], acc[4 + ct], 0, 0, 0);
        }
    }

    const bool valid = rbase < N_VOX;   // N_VOX % 32 == 0: whole wave-tile valid or not

    // store h
    if (valid) {
#pragma unroll
        for (int t = 0; t < 2; ++t) {
            float* hp = h + (long)(rbase + t * 16 + quad * 4) * 64 + m;
#pragma unroll
            for (int r = 0; r < 4; ++r) {
#pragma unroll
                for (int ct = 0; ct < 4; ++ct)
                    hp[r * 64 + ct * 16] = acc[t * 4 + ct][r];
            }
        }
    }

    // fused BN stats: per-channel sum / sumsq over this wave's 32 rows
    __shared__ float lsum[16][64];
    __shared__ float lsq[16][64];
#pragma unroll
    for (int ct = 0; ct < 4; ++ct) {
        float s = 0.f, q = 0.f;
        if (valid) {
#pragma unroll
            for (int t = 0; t < 2; ++t)
#pragma unroll
                for (int r = 0; r < 4; ++r) {
                    float v = acc[t * 4 + ct][r];
                    s += v; q += v * v;
                }
        }
        lsum[wave * 4 + quad][ct * 16 + m] = s;
        lsq [wave * 4 + quad][ct * 16 + m] = q;
    }
    __syncthreads();
    if (tid < 64) {
        float S = 0.f, Q = 0.f;
#pragma unroll
        for (int j = 0; j < 16; ++j) { S += lsum[j][tid]; Q += lsq[j][tid]; }
        atomicAdd(&sums[tid], S);
        atomicAdd(&sums[64 + tid], Q);
    }
}

// ---------------- BN1 + relu + cast to bf16 (conv2 input) ----------------

__global__ void bnrelu_kernel(const float* __restrict__ h, const float* __restrict__ sums,
                              const float* __restrict__ gamma, const float* __restrict__ beta,
                              __hip_bfloat16* __restrict__ hb) {
    long i = ((long)blockIdx.x * 256 + threadIdx.x) * 4;
    if (i >= (long)(N_VOX + 1) * 64) return;
    __hip_bfloat16 t[4];
    if (i < (long)N_VOX * 64) {
        int c0 = (int)(i & 63);
        float4 v = *(const float4*)(h + i);
        float vv[4] = {v.x, v.y, v.z, v.w};
#pragma unroll
        for (int j = 0; j < 4; ++j) {
            int c = c0 + j;
            float mu  = sums[c] * (1.0f / N_VOX);
            float var = sums[64 + c] * (1.0f / N_VOX) - mu * mu;
            float rs  = rsqrtf(var + EPS_BN);
            float val = gamma[c] * (vv[j] - mu) * rs + beta[c];
            t[j] = __float2bfloat16(fmaxf(val, 0.0f));
        }
    } else {
        t[0] = t[1] = t[2] = t[3] = __float2bfloat16(0.0f);   // zero row N
    }
    *(ushort4*)(hb + i) = *(ushort4*)t;
}

// ---------------- BN2 + residual + relu -> d_out ----------------

__global__ void final_kernel(const float* __restrict__ h, const float* __restrict__ x,
                             const float* __restrict__ sums, const float* __restrict__ gamma,
                             const float* __restrict__ beta, float* __restrict__ out) {
    long i = ((long)blockIdx.x * 256 + threadIdx.x) * 4;
    if (i >= (long)N_VOX * 64) return;
    int c0 = (int)(i & 63);
    float4 v  = *(const float4*)(h + i);
    float4 xr = *(const float4*)(x + i);
    float vv[4] = {v.x, v.y, v.z, v.w};
    float xx[4] = {xr.x, xr.y, xr.z, xr.w};
    float oo[4];
#pragma unroll
    for (int j = 0; j < 4; ++j) {
        int c = c0 + j;
        float mu  = sums[c] * (1.0f / N_VOX);
        float var = sums[64 + c] * (1.0f / N_VOX) - mu * mu;
        float rs  = rsqrtf(var + EPS_BN);
        float val = gamma[c] * (vv[j] - mu) * rs + beta[c] + xx[j];
        oo[j] = fmaxf(val, 0.0f);
    }
    float4 ov = {oo[0], oo[1], oo[2], oo[3]};
    *(float4*)(out + i) = ov;
}

// ---------------- launcher ----------------

extern "C" void kernel_launch(void* const* d_in, const int* in_sizes, int n_in,
                              void* d_out, int out_size, void* d_ws, size_t ws_size,
                              hipStream_t stream) {
    const float* x      = (const float*)d_in[0];
    const float* W1     = (const float*)d_in[1];
    const float* gamma1 = (const float*)d_in[2];
    const float* beta1  = (const float*)d_in[3];
    const float* W2     = (const float*)d_in[4];
    const float* gamma2 = (const float*)d_in[5];
    const float* beta2  = (const float*)d_in[6];
    const int* in_maps  = (const int*)d_in[7];
    const int* out_maps = (const int*)d_in[8];
    float* out = (float*)d_out;

    char* ws = (char*)d_ws;
    size_t off = 0;
    auto alloc = [&](size_t bytes) -> void* {
        void* p = ws + off;
        off = (off + bytes + 255) & ~(size_t)255;
        return p;
    };
    int* nbrT           = (int*)alloc((size_t)27 * NP * 4);                    // 21.6 MB
    __hip_bfloat16* xb  = (__hip_bfloat16*)alloc((size_t)(N_VOX + 1) * 64 * 2); // 25.6 MB (reused as h1b)
    __hip_bfloat16* W1T = (__hip_bfloat16*)alloc((size_t)27 * 4096 * 2);
    __hip_bfloat16* W2T = (__hip_bfloat16*)alloc((size_t)27 * 4096 * 2);
    float* h            = (float*)alloc((size_t)N_VOX * 64 * 4);               // 51.2 MB
    float* sums         = (float*)alloc(256 * 4);
    __hip_bfloat16* h1b = xb;   // xb dead after conv1; reuse for BN1(relu) output

    const long elem_x = (long)(N_VOX + 1) * 64;

    fill_kernel   <<<dim3((NP / 4 + 255) / 256, 27), 256, 0, stream>>>(nbrT, sums);
    scatter_kernel<<<26 * P_PAIR / 256, 256, 0, stream>>>(out_maps, in_maps, nbrT);
    cast_x_kernel <<<(int)((elem_x / 4 + 255) / 256), 256, 0, stream>>>(x, xb);
    cast_w_kernel <<<(27 * 4096 + 255) / 256, 256, 0, stream>>>(W1, W2, W1T, W2T);

    conv_kernel   <<<NP / 128, 256, 0, stream>>>(xb, W1T, nbrT, h, sums);
    bnrelu_kernel <<<(int)((elem_x / 4 + 255) / 256), 256, 0, stream>>>(h, sums, gamma1, beta1, h1b);

    conv_kernel   <<<NP / 128, 256, 0, stream>>>(h1b, W2T, nbrT, h, sums + 128);
    final_kernel  <<<(int)(((long)N_VOX * 64 / 4 + 255) / 256), 256, 0, stream>>>(h, x, sums + 128, gamma2, beta2, out);
}